// Round 2
// baseline (613.149 us; speedup 1.0000x reference)
//
#include <hip/hip_runtime.h>
#include <hip/hip_cooperative_groups.h>

namespace cg = cooperative_groups;

#define D 128
#define BN_EPS 1e-5f
#define CHUNK 2048           // edges per scatter work-item (256 thr x 8)
#define NBSH 7               // bucket = dst >> 7  (128 rows per bucket)
#define CAP 3584             // padded bucket capacity (mean 2048, +34 sigma)
#define AST 136              // bf16 LDS row stride (128+8, keeps 16B alignment)

typedef __attribute__((ext_vector_type(8))) short bf16x8;
typedef __attribute__((ext_vector_type(4))) float f32x4;

// RNE round f32 -> bf16
__device__ __forceinline__ unsigned short bf16r(float a) {
    unsigned u = __float_as_uint(a);
    u += 0x7fff + ((u >> 16) & 1);
    return (unsigned short)(u >> 16);
}
__device__ __forceinline__ unsigned bf16pairp(float a, float b) {
    return (unsigned)bf16r(a) | ((unsigned)bf16r(b) << 16);
}

union Smem {
    struct { unsigned short B[128 * AST]; float scsh[256]; } g;  // gemm: 35840 B
    struct { int h[512]; int sh[256]; } s;                       // scatter/csr
    float bn[256];                                               // agg BN partials
};

struct P {
    const int* src; const int* dst;
    const float* x; const float* W1; const float* gamma; const float* beta;
    const float* W2; const float* b2;
    float* out;
    float* agg; unsigned short* hbf; float* dinv;
    int* rowptr; int* rowcnt; int* bcur; float* sums;
    int2* bpairs; int* csr;
    int n, E, nb, nchunks, ntiles, scatB;
};

// ---------------- phase: bucket scatter of (src,dst) pairs ----------------
__device__ __forceinline__ void ph_scatter(const P& p, Smem& sm, int bid, int nblk) {
    int tid = threadIdx.x;
    for (int ch = bid; ch < p.nchunks; ch += nblk) {
        __syncthreads();                     // protect smem reuse across items
        sm.s.h[tid] = 0; sm.s.h[tid + 256] = 0;
        __syncthreads();
        int base = ch * CHUNK + tid;
        int s[8], t[8], r[8];
#pragma unroll
        for (int k = 0; k < 8; k++) {
            int i = base + k * 256;
            if (i < p.E) {
                s[k] = p.src[i];
                t[k] = p.dst[i];
                r[k] = atomicAdd(&sm.s.h[t[k] >> NBSH], 1);
            } else {
                t[k] = -1;
            }
        }
        __syncthreads();
        for (int b = tid; b < 512; b += 256) {
            int c = sm.s.h[b];
            sm.s.h[b] = c ? atomicAdd(&p.bcur[b], c) : 0;
        }
        __syncthreads();
#pragma unroll
        for (int k = 0; k < 8; k++) {
            if (t[k] >= 0) {
                int b = t[k] >> NBSH;
                int pos = sm.s.h[b] + r[k];
                if (pos < CAP) p.bpairs[(size_t)b * CAP + pos] = make_int2(s[k], t[k]);
            }
        }
    }
}

// ---------------- phase: per-bucket CSR finalize ----------------
__device__ __forceinline__ void ph_csr(const P& p, Smem& sm, int bid, int nblk) {
    int tid = threadIdx.x;
    for (int b = bid; b < p.nb; b += nblk) {
        __syncthreads();
        size_t lo = (size_t)b * CAP;
        int cnt = p.bcur[b];
        if (cnt > CAP) cnt = CAP;
        sm.s.h[tid] = 0;
        __syncthreads();
        for (int i = tid; i < cnt; i += 256) atomicAdd(&sm.s.h[p.bpairs[lo + i].y & 127], 1);
        __syncthreads();
        int c = (tid < 128) ? sm.s.h[tid] : 0;
        sm.s.sh[tid] = c;
        __syncthreads();
        for (int off = 1; off < 128; off <<= 1) {
            int u = (tid >= off && tid < 128) ? sm.s.sh[tid - off] : 0;
            __syncthreads();
            if (tid < 128) sm.s.sh[tid] += u;
            __syncthreads();
        }
        int ex = sm.s.sh[tid] - c;
        int row = b * 128 + tid;
        if (tid < 128 && row < p.n) {
            p.rowptr[row] = (int)lo + ex;
            p.rowcnt[row] = c;
            p.dinv[row] = rsqrtf((float)(c + 1));   // +1 = self loop
        }
        __syncthreads();
        if (tid < 128) sm.s.h[tid] = (int)lo + ex;  // reuse as cursor
        __syncthreads();
        for (int i = tid; i < cnt; i += 256) {
            int2 pr = p.bpairs[lo + i];
            int pos = atomicAdd(&sm.s.h[pr.y & 127], 1);
            p.csr[pos] = pr.x;
        }
    }
}

// ---------------- phase: MFMA GEMM, W staged once/block, A from global regs ----
// Yb = bf16( f(X) @ W );  f = identity | relu(x*scale+shift) (BN from sums)
__device__ __forceinline__ void ph_gemm(const P& p, Smem& sm,
                                        const float* __restrict__ X,
                                        const float* __restrict__ W,
                                        bool bn, unsigned short* __restrict__ Yb,
                                        int bid0, int nblk) {
    int tid = threadIdx.x;
    // stage W^T bf16 -> sm.g.B[c*AST + k] (in-block transpose, coalesced on k)
#pragma unroll
    for (int pp = 0; pp < 16; pp++) {
        int idx = tid + pp * 256;
        int c = idx & 127, k0 = (idx >> 7) * 4;
        float w0 = W[(size_t)(k0 + 0) * D + c];
        float w1 = W[(size_t)(k0 + 1) * D + c];
        float w2 = W[(size_t)(k0 + 2) * D + c];
        float w3 = W[(size_t)(k0 + 3) * D + c];
        uint2 pk;
        pk.x = bf16pairp(w0, w1);
        pk.y = bf16pairp(w2, w3);
        *(uint2*)&sm.g.B[c * AST + k0] = pk;
    }
    if (bn && tid < D) {
        float inv_n = 1.0f / (float)p.n;
        float mu = p.sums[tid] * inv_n;
        float var = p.sums[D + tid] * inv_n - mu * mu;
        float is = rsqrtf(var + BN_EPS);
        float scl = p.gamma[tid] * is;
        sm.g.scsh[tid] = scl;
        sm.g.scsh[D + tid] = p.beta[tid] - mu * scl;
    }
    __syncthreads();
    int w = tid >> 6, lane = tid & 63;
    int m = lane & 15, quad = lane >> 4;
    for (int tile = bid0; tile < p.ntiles; tile += nblk) {
        int row = tile * 64 + w * 16 + m;
        bool ok = row < p.n;
        const float* Xr = X + (size_t)(ok ? row : 0) * D;
        bf16x8 av[4];
#pragma unroll
        for (int ks = 0; ks < 4; ks++) {
            int c0 = ks * 32 + quad * 8;
            float4 a = ok ? *(const float4*)(Xr + c0)     : make_float4(0.f,0.f,0.f,0.f);
            float4 b = ok ? *(const float4*)(Xr + c0 + 4) : make_float4(0.f,0.f,0.f,0.f);
            if (bn) {
                float4 s0 = *(const float4*)&sm.g.scsh[c0];
                float4 s1 = *(const float4*)&sm.g.scsh[c0 + 4];
                float4 h0 = *(const float4*)&sm.g.scsh[D + c0];
                float4 h1 = *(const float4*)&sm.g.scsh[D + c0 + 4];
                a.x = fmaxf(fmaf(a.x, s0.x, h0.x), 0.f);
                a.y = fmaxf(fmaf(a.y, s0.y, h0.y), 0.f);
                a.z = fmaxf(fmaf(a.z, s0.z, h0.z), 0.f);
                a.w = fmaxf(fmaf(a.w, s0.w, h0.w), 0.f);
                b.x = fmaxf(fmaf(b.x, s1.x, h1.x), 0.f);
                b.y = fmaxf(fmaf(b.y, s1.y, h1.y), 0.f);
                b.z = fmaxf(fmaf(b.z, s1.z, h1.z), 0.f);
                b.w = fmaxf(fmaf(b.w, s1.w, h1.w), 0.f);
            }
            union { bf16x8 v; unsigned u[4]; } cvt;
            cvt.u[0] = bf16pairp(a.x, a.y);
            cvt.u[1] = bf16pairp(a.z, a.w);
            cvt.u[2] = bf16pairp(b.x, b.y);
            cvt.u[3] = bf16pairp(b.z, b.w);
            av[ks] = cvt.v;
        }
        f32x4 acc[8];
#pragma unroll
        for (int ct = 0; ct < 8; ct++) acc[ct] = (f32x4){0.f, 0.f, 0.f, 0.f};
#pragma unroll
        for (int ct = 0; ct < 8; ct++) {
#pragma unroll
            for (int ks = 0; ks < 4; ks++) {
                bf16x8 bv = *(const bf16x8*)&sm.g.B[(ct * 16 + m) * AST + ks * 32 + quad * 8];
                acc[ct] = __builtin_amdgcn_mfma_f32_16x16x32_bf16(av[ks], bv, acc[ct], 0, 0, 0);
            }
        }
        int rb = tile * 64 + w * 16 + quad * 4;
#pragma unroll
        for (int ct = 0; ct < 8; ct++) {
#pragma unroll
            for (int r = 0; r < 4; r++) {
                int grow = rb + r;
                if (grow < p.n)
                    Yb[(size_t)grow * D + ct * 16 + m] = bf16r(acc[ct][r]);
            }
        }
    }
}

// ---------------- phase: slot-gather aggregation (+optional fused BN stats) ---
// OUT[t] = ( dinv[t]*Hb[t] + sum_{s in N(t)} dinv[s]*Hb[s] ) * dinv[t] + bias
__device__ __forceinline__ void unpack_fma(uint4 u, float d, float* acc) {
    acc[0] = fmaf(d, __uint_as_float(u.x << 16), acc[0]);
    acc[1] = fmaf(d, __uint_as_float(u.x & 0xffff0000u), acc[1]);
    acc[2] = fmaf(d, __uint_as_float(u.y << 16), acc[2]);
    acc[3] = fmaf(d, __uint_as_float(u.y & 0xffff0000u), acc[3]);
    acc[4] = fmaf(d, __uint_as_float(u.z << 16), acc[4]);
    acc[5] = fmaf(d, __uint_as_float(u.z & 0xffff0000u), acc[5]);
    acc[6] = fmaf(d, __uint_as_float(u.w << 16), acc[6]);
    acc[7] = fmaf(d, __uint_as_float(u.w & 0xffff0000u), acc[7]);
}

__device__ __forceinline__ void ph_agg(const P& p, Smem& sm,
                                       const unsigned short* __restrict__ Hb,
                                       const float* __restrict__ bias,
                                       float* __restrict__ OUT,
                                       bool doBN, int bid, int nblk) {
    int tid = threadIdx.x;
    if (doBN) sm.bn[tid] = 0.f;
    __syncthreads();
    int wv = tid >> 6, lane = tid & 63;
    int slot = lane >> 4, seg = lane & 15;
    const uint4* HB4 = (const uint4*)Hb;
    int nrg = (p.n + 3) >> 2;
    for (int rg = bid; rg < nrg; rg += nblk) {
        int row = rg * 4 + wv;
        if (row >= p.n) continue;            // wave-uniform; no barriers below
        float dt = p.dinv[row];
        float acc[8];
#pragma unroll
        for (int i = 0; i < 8; i++) acc[i] = 0.f;
        if (slot == 0) {                     // self term, weight dinv[row]
            uint4 us = HB4[(size_t)row * 16 + seg];
            unpack_fma(us, dt, acc);
        }
        int k0 = p.rowptr[row];
        int deg = p.rowcnt[row];
        int iters = deg >> 2;
        int k = k0 + slot;
        int it = 0;
        for (; it + 4 <= iters; it += 4, k += 16) {
            int s0 = p.csr[k], s1 = p.csr[k + 4];
            int s2 = p.csr[k + 8], s3 = p.csr[k + 12];
            float d0 = p.dinv[s0], d1 = p.dinv[s1], d2 = p.dinv[s2], d3 = p.dinv[s3];
            uint4 u0 = HB4[(size_t)s0 * 16 + seg];
            uint4 u1 = HB4[(size_t)s1 * 16 + seg];
            uint4 u2 = HB4[(size_t)s2 * 16 + seg];
            uint4 u3 = HB4[(size_t)s3 * 16 + seg];
            unpack_fma(u0, d0, acc);
            unpack_fma(u1, d1, acc);
            unpack_fma(u2, d2, acc);
            unpack_fma(u3, d3, acc);
        }
        for (; it < iters; it++, k += 4) {
            int s = p.csr[k];
            float d = p.dinv[s];
            uint4 u = HB4[(size_t)s * 16 + seg];
            unpack_fma(u, d, acc);
        }
        if (slot < (deg & 3)) {              // tail edges
            int s = p.csr[k];
            float d = p.dinv[s];
            uint4 u = HB4[(size_t)s * 16 + seg];
            unpack_fma(u, d, acc);
        }
#pragma unroll
        for (int i = 0; i < 8; i++) {
            acc[i] += __shfl_xor(acc[i], 16, 64);
            acc[i] += __shfl_xor(acc[i], 32, 64);
        }
        float v0 = acc[slot * 2] * dt;
        float v1 = acc[slot * 2 + 1] * dt;
        int cp = seg * 4 + slot;             // float2 index = col/2
        if (bias) {
            float2 b = ((const float2*)bias)[cp];
            v0 += b.x;
            v1 += b.y;
        }
        ((float2*)OUT)[(size_t)row * 64 + cp] = make_float2(v0, v1);
        if (doBN) {
            int c0 = cp * 2;
            atomicAdd(&sm.bn[c0], v0);
            atomicAdd(&sm.bn[c0 + 1], v1);
            atomicAdd(&sm.bn[128 + c0], v0 * v0);
            atomicAdd(&sm.bn[128 + c0 + 1], v1 * v1);
        }
    }
    __syncthreads();
    if (doBN) atomicAdd(&p.sums[tid], sm.bn[tid]);
}

// ---------------- cooperative mega-kernel ----------------
__global__ __launch_bounds__(256, 4) void k_mega(P p) {
    __shared__ Smem sm;
    cg::grid_group g = cg::this_grid();
    int bid = blockIdx.x, G = gridDim.x;
    // P1: edge scatter || GEMM1 (independent: payload unscaled, dinv in agg)
    if (bid < p.scatB) ph_scatter(p, sm, bid, p.scatB);
    else ph_gemm(p, sm, p.x, p.W1, false, p.hbf, bid - p.scatB, G - p.scatB);
    g.sync();
    // P2: CSR finalize (rowptr/rowcnt/dinv/csr)
    ph_csr(p, sm, bid, G);
    g.sync();
    // P3: agg1 -> agg, fused BN stats -> sums
    ph_agg(p, sm, p.hbf, nullptr, p.agg, true, bid, G);
    g.sync();
    // P4: GEMM2 (BN finalize + relu fused into A load)
    ph_gemm(p, sm, p.agg, p.W2, true, p.hbf, bid, G);
    g.sync();
    // P5: agg2 + b2 -> out
    ph_agg(p, sm, p.hbf, p.b2, p.out, false, bid, G);
}

// ---------------- fallback: same phases as ordinary kernels ----------------
__global__ __launch_bounds__(256, 4) void k_phase(P p, int ph) {
    __shared__ Smem sm;
    int bid = blockIdx.x, G = gridDim.x;
    switch (ph) {
        case 1:
            if (bid < p.scatB) ph_scatter(p, sm, bid, p.scatB);
            else ph_gemm(p, sm, p.x, p.W1, false, p.hbf, bid - p.scatB, G - p.scatB);
            break;
        case 2: ph_csr(p, sm, bid, G); break;
        case 3: ph_agg(p, sm, p.hbf, nullptr, p.agg, true, bid, G); break;
        case 4: ph_gemm(p, sm, p.agg, p.W2, true, p.hbf, bid, G); break;
        case 5: ph_agg(p, sm, p.hbf, p.b2, p.out, false, bid, G); break;
    }
}

extern "C" void kernel_launch(void* const* d_in, const int* in_sizes, int n_in,
                              void* d_out, int out_size, void* d_ws, size_t ws_size,
                              hipStream_t stream) {
    const float* x     = (const float*)d_in[0];
    const int*   ei    = (const int*)d_in[1];
    const float* W1    = (const float*)d_in[2];
    // d_in[3] = b1 — cancels exactly in BatchNorm, unused
    const float* gamma = (const float*)d_in[4];
    const float* beta  = (const float*)d_in[5];
    const float* W2    = (const float*)d_in[6];
    const float* b2    = (const float*)d_in[7];

    int n = in_sizes[0] / D;   // 50000
    int E = in_sizes[1] / 2;   // 800000
    int nb = (n + 127) >> NBSH;          // 391 buckets (<= 512)
    int nchunks = (E + CHUNK - 1) / CHUNK;
    int ntiles = (n + 63) / 64;

    char* ws = (char*)d_ws;
    size_t off = 0;
    auto alloc = [&](size_t bytes) {
        char* p = ws + off;
        off = (off + bytes + 511) & ~(size_t)511;
        return p;
    };
    float*          agg    = (float*)alloc((size_t)n * D * sizeof(float));
    unsigned short* hbf    = (unsigned short*)alloc((size_t)n * D * 2);
    float*          dinv   = (float*)alloc(n * sizeof(float));
    int*            rowptr = (int*)alloc(n * sizeof(int));
    int*            rowcnt = (int*)alloc(n * sizeof(int));
    int*            bcur   = (int*)alloc(768 * sizeof(int));  // bcur[512]+sums[256]
    float*          sums   = (float*)(bcur + 512);
    int2*           bpairs = (int2*)alloc((size_t)nb * CAP * sizeof(int2));
    int*            csr    = (int*)alloc((size_t)nb * CAP * sizeof(int));

    // grid size: co-residency capacity (computed once)
    static int g_grid = 0;
    if (g_grid == 0) {
        int perCU = 0;
        hipOccupancyMaxActiveBlocksPerMultiprocessor(&perCU, k_mega, 256, 0);
        if (perCU < 1) perCU = 1;
        int cus = 256;
        hipDeviceGetAttribute(&cus, hipDeviceAttributeMultiprocessorCount, 0);
        g_grid = perCU * cus;
        if (g_grid > 2048) g_grid = 2048;
    }
    int G = g_grid;

    P p;
    p.src = ei; p.dst = ei + E;
    p.x = x; p.W1 = W1; p.gamma = gamma; p.beta = beta; p.W2 = W2; p.b2 = b2;
    p.out = (float*)d_out;
    p.agg = agg; p.hbf = hbf; p.dinv = dinv;
    p.rowptr = rowptr; p.rowcnt = rowcnt; p.bcur = bcur; p.sums = sums;
    p.bpairs = bpairs; p.csr = csr;
    p.n = n; p.E = E; p.nb = nb; p.nchunks = nchunks; p.ntiles = ntiles;
    p.scatB = G / 4;

    // zero bucket cursors + BN sums (single tiny fill)
    hipMemsetAsync(bcur, 0, 768 * sizeof(int), stream);

    static int g_coop = -1;   // -1 unknown, 1 works, 0 fall back
    bool done = false;
    if (g_coop != 0) {
        void* args[] = { &p };
        hipError_t e = hipLaunchCooperativeKernel((void*)k_mega, dim3(G), dim3(256),
                                                  args, 0, stream);
        if (e == hipSuccess) { g_coop = 1; done = true; }
        else g_coop = 0;
    }
    if (!done) {
        for (int ph = 1; ph <= 5; ph++)
            hipLaunchKernelGGL(k_phase, dim3(G), dim3(256), 0, stream, p, ph);
    }
}

// Round 3
// 257.123 us; speedup vs baseline: 2.3847x; 2.3847x over previous
//
#include <hip/hip_runtime.h>

#define D 128
#define BN_EPS 1e-5f
#define CHUNK 2048           // edges per build block (256 thr x 8)
#define RCAP 64              // padded CSR row capacity (deg ~ Poisson(16); P(>=64) ~ 1e-18)
#define NPART 64             // BN partial-sum partitions
#define AST 136              // bf16 LDS row stride (128+8, keeps 16B alignment)

typedef __attribute__((ext_vector_type(8))) short bf16x8;
typedef __attribute__((ext_vector_type(4))) float f32x4;

// RNE round f32 -> bf16
__device__ __forceinline__ unsigned short bf16r(float a) {
    unsigned u = __float_as_uint(a);
    u += 0x7fff + ((u >> 16) & 1);
    return (unsigned short)(u >> 16);
}
__device__ __forceinline__ unsigned bf16pairp(float a, float b) {
    return (unsigned)bf16r(a) | ((unsigned)bf16r(b) << 16);
}

// ---------------- GEMM tile body (A in registers, B staged once in LDS) -------
// Yb[64 rows @ tile*64] = bf16( f(X) @ W ), W f32 row-major [k][c].
// f = identity when sums_part==null, else relu(x*scale+shift); BN scale/shift
// computed in-block by reducing the NPART partial sums (fused finalize).
__device__ __forceinline__ void gemm_tile(int tile, const float* __restrict__ X,
                                          const float* __restrict__ W,
                                          const float* __restrict__ sums_part,
                                          const float* __restrict__ gamma,
                                          const float* __restrict__ beta,
                                          unsigned short* __restrict__ Yb, int n,
                                          unsigned short* Bbf, float* scsh, int tid) {
    // stage W^T bf16 -> Bbf[c*AST + k] (in-block transpose, coalesced on c)
#pragma unroll
    for (int pp = 0; pp < 16; pp++) {
        int idx = tid + pp * 256;           // 0..4095
        int c = idx & 127, k0 = (idx >> 7) * 4;
        float w0 = W[(size_t)(k0 + 0) * D + c];
        float w1 = W[(size_t)(k0 + 1) * D + c];
        float w2 = W[(size_t)(k0 + 2) * D + c];
        float w3 = W[(size_t)(k0 + 3) * D + c];
        uint2 pk;
        pk.x = bf16pairp(w0, w1);
        pk.y = bf16pairp(w2, w3);
        *(uint2*)&Bbf[c * AST + k0] = pk;
    }
    bool bn = (sums_part != nullptr);
    if (bn) {
        float accp = 0.f;
#pragma unroll
        for (int pp = 0; pp < NPART; pp++) accp += sums_part[pp * 256 + tid];
        scsh[tid] = accp;
        __syncthreads();
        if (tid < D) {
            float inv_n = 1.0f / (float)n;
            float mu = scsh[tid] * inv_n;
            float var = scsh[D + tid] * inv_n - mu * mu;
            float is = rsqrtf(var + BN_EPS);
            float scl = gamma[tid] * is;
            float sh = beta[tid] - mu * scl;
            scsh[tid] = scl;                // each tid<128 reads/writes only its
            scsh[D + tid] = sh;             // own two entries: no race
        }
    }
    __syncthreads();

    int w = tid >> 6, lane = tid & 63;
    int m = lane & 15, quad = lane >> 4;
    int row = tile * 64 + w * 16 + m;
    bool ok = row < n;
    const float* Xr = X + (size_t)(ok ? row : 0) * D;
    bf16x8 av[4];
#pragma unroll
    for (int ks = 0; ks < 4; ks++) {
        int c0 = ks * 32 + quad * 8;
        float4 a = ok ? *(const float4*)(Xr + c0)     : make_float4(0.f, 0.f, 0.f, 0.f);
        float4 b = ok ? *(const float4*)(Xr + c0 + 4) : make_float4(0.f, 0.f, 0.f, 0.f);
        if (bn) {
            float4 s0 = *(const float4*)&scsh[c0];
            float4 s1 = *(const float4*)&scsh[c0 + 4];
            float4 h0 = *(const float4*)&scsh[D + c0];
            float4 h1 = *(const float4*)&scsh[D + c0 + 4];
            a.x = fmaxf(fmaf(a.x, s0.x, h0.x), 0.f);
            a.y = fmaxf(fmaf(a.y, s0.y, h0.y), 0.f);
            a.z = fmaxf(fmaf(a.z, s0.z, h0.z), 0.f);
            a.w = fmaxf(fmaf(a.w, s0.w, h0.w), 0.f);
            b.x = fmaxf(fmaf(b.x, s1.x, h1.x), 0.f);
            b.y = fmaxf(fmaf(b.y, s1.y, h1.y), 0.f);
            b.z = fmaxf(fmaf(b.z, s1.z, h1.z), 0.f);
            b.w = fmaxf(fmaf(b.w, s1.w, h1.w), 0.f);
        }
        union { bf16x8 v; unsigned u[4]; } cvt;
        cvt.u[0] = bf16pairp(a.x, a.y);
        cvt.u[1] = bf16pairp(a.z, a.w);
        cvt.u[2] = bf16pairp(b.x, b.y);
        cvt.u[3] = bf16pairp(b.z, b.w);
        av[ks] = cvt.v;
    }
    f32x4 acc[8];
#pragma unroll
    for (int ct = 0; ct < 8; ct++) acc[ct] = (f32x4){0.f, 0.f, 0.f, 0.f};
#pragma unroll
    for (int ct = 0; ct < 8; ct++) {
#pragma unroll
        for (int ks = 0; ks < 4; ks++) {
            bf16x8 bv = *(const bf16x8*)&Bbf[(ct * 16 + m) * AST + ks * 32 + quad * 8];
            acc[ct] = __builtin_amdgcn_mfma_f32_16x16x32_bf16(av[ks], bv, acc[ct], 0, 0, 0);
        }
    }
    int rb = tile * 64 + w * 16 + quad * 4;
#pragma unroll
    for (int ct = 0; ct < 8; ct++) {
#pragma unroll
        for (int r = 0; r < 4; r++) {
            int grow = rb + r;
            if (grow < n)
                Yb[(size_t)grow * D + ct * 16 + m] = bf16r(acc[ct][r]);
        }
    }
}

// ---------------- k_build: padded-CSR scatter || GEMM1 ----------------
// blocks [0,nchunks): csr[dst*RCAP + atomicAdd(rowcnt[dst])] = src  (no scan,
// no pair buffer, no finalize pass). blocks [nchunks,..): GEMM1 tiles
// (independent: payload unscaled; norm applied per-edge in aggregation).
__global__ __launch_bounds__(256) void k_build(const int* __restrict__ src,
                                               const int* __restrict__ dst,
                                               int* __restrict__ rowcnt,
                                               int* __restrict__ csr,
                                               int E, int nchunks,
                                               const float* __restrict__ X,
                                               const float* __restrict__ W1,
                                               unsigned short* __restrict__ Yb, int n) {
    __shared__ unsigned short Bbf[128 * AST];
    int tid = threadIdx.x;
    if (blockIdx.x >= nchunks) {
        gemm_tile(blockIdx.x - nchunks, X, W1, nullptr, nullptr, nullptr,
                  Yb, n, Bbf, nullptr, tid);
        return;
    }
    int base = blockIdx.x * CHUNK + tid;
#pragma unroll
    for (int k = 0; k < 8; k++) {
        int i = base + k * 256;
        if (i < E) {
            int s = src[i];
            int t = dst[i];
            int slot = atomicAdd(&rowcnt[t], 1);
            if (slot < RCAP) csr[(size_t)t * RCAP + slot] = s;
        }
    }
}

// ---------------- slot-gather aggregation (+fused BN partial stats) ----------
// OUT[t] = ( dinv[t]*Hb[t] + sum_{s in N(t)} dinv[s]*Hb[s] ) * dinv[t] + bias
// dinv[r] = rsqrtf(rowcnt[r]+1) computed on the fly (VALU is idle; kills the
// dinv array and its producer pass).
__device__ __forceinline__ void unpack_fma(uint4 u, float d, float* acc) {
    acc[0] = fmaf(d, __uint_as_float(u.x << 16), acc[0]);
    acc[1] = fmaf(d, __uint_as_float(u.x & 0xffff0000u), acc[1]);
    acc[2] = fmaf(d, __uint_as_float(u.y << 16), acc[2]);
    acc[3] = fmaf(d, __uint_as_float(u.y & 0xffff0000u), acc[3]);
    acc[4] = fmaf(d, __uint_as_float(u.z << 16), acc[4]);
    acc[5] = fmaf(d, __uint_as_float(u.z & 0xffff0000u), acc[5]);
    acc[6] = fmaf(d, __uint_as_float(u.w << 16), acc[6]);
    acc[7] = fmaf(d, __uint_as_float(u.w & 0xffff0000u), acc[7]);
}

__global__ __launch_bounds__(256) void k_agg(const unsigned short* __restrict__ Hb,
                                             const int* __restrict__ csr,
                                             const int* __restrict__ rowcnt,
                                             const float* __restrict__ bias,
                                             float* __restrict__ OUT,
                                             float* __restrict__ sums_part, int n) {
    __shared__ float bn[256];
    int tid = threadIdx.x;
    bool doBN = (sums_part != nullptr);
    if (doBN) {
        bn[tid] = 0.f;
        __syncthreads();
    }
    int row = blockIdx.x * 4 + (tid >> 6);
    if (row < n) {
        int lane = tid & 63;
        int slot = lane >> 4, seg = lane & 15;
        const uint4* HB4 = (const uint4*)Hb;
        int cnt = rowcnt[row];
        float dt = rsqrtf((float)(cnt + 1));
        int deg = (cnt < RCAP) ? cnt : RCAP;
        const int* cr = csr + (size_t)row * RCAP;

        float acc[8];
#pragma unroll
        for (int i = 0; i < 8; i++) acc[i] = 0.f;
        if (slot == 0) {                       // self term, weight dinv[row]
            uint4 us = HB4[(size_t)row * 16 + seg];
            unpack_fma(us, dt, acc);
        }
        int iters = deg >> 2;
        int k = slot;
        int it = 0;
        for (; it + 4 <= iters; it += 4, k += 16) {
            int s0 = cr[k], s1 = cr[k + 4];
            int s2 = cr[k + 8], s3 = cr[k + 12];
            float d0 = rsqrtf((float)(rowcnt[s0] + 1));
            float d1 = rsqrtf((float)(rowcnt[s1] + 1));
            float d2 = rsqrtf((float)(rowcnt[s2] + 1));
            float d3 = rsqrtf((float)(rowcnt[s3] + 1));
            uint4 u0 = HB4[(size_t)s0 * 16 + seg];
            uint4 u1 = HB4[(size_t)s1 * 16 + seg];
            uint4 u2 = HB4[(size_t)s2 * 16 + seg];
            uint4 u3 = HB4[(size_t)s3 * 16 + seg];
            unpack_fma(u0, d0, acc);
            unpack_fma(u1, d1, acc);
            unpack_fma(u2, d2, acc);
            unpack_fma(u3, d3, acc);
        }
        for (; it < iters; it++, k += 4) {
            int s = cr[k];
            float d = rsqrtf((float)(rowcnt[s] + 1));
            uint4 u = HB4[(size_t)s * 16 + seg];
            unpack_fma(u, d, acc);
        }
        if (slot < (deg & 3)) {                // tail edges
            int s = cr[k];
            float d = rsqrtf((float)(rowcnt[s] + 1));
            uint4 u = HB4[(size_t)s * 16 + seg];
            unpack_fma(u, d, acc);
        }
#pragma unroll
        for (int i = 0; i < 8; i++) {
            acc[i] += __shfl_xor(acc[i], 16, 64);
            acc[i] += __shfl_xor(acc[i], 32, 64);
        }
        float v0 = acc[slot * 2] * dt;
        float v1 = acc[slot * 2 + 1] * dt;
        int cp = seg * 4 + slot;               // float2 index = col/2
        if (bias) {
            float2 b = ((const float2*)bias)[cp];
            v0 += b.x;
            v1 += b.y;
        }
        ((float2*)OUT)[(size_t)row * 64 + cp] = make_float2(v0, v1);
        if (doBN) {
            int c0 = cp * 2;                   // 64 lanes -> 64 distinct even
            atomicAdd(&bn[c0], v0);            // offsets: 2-way bank alias, free
            atomicAdd(&bn[c0 + 1], v1);
            atomicAdd(&bn[128 + c0], v0 * v0);
            atomicAdd(&bn[128 + c0 + 1], v1 * v1);
        }
    }
    if (doBN) {
        __syncthreads();
        atomicAdd(&sums_part[(blockIdx.x & (NPART - 1)) * 256 + tid], bn[tid]);
    }
}

// ---------------- GEMM2: BN finalize + relu fused ----------------
__global__ __launch_bounds__(256) void k_gemm2(const float* __restrict__ X,
                                               const float* __restrict__ W,
                                               const float* __restrict__ sums_part,
                                               const float* __restrict__ gamma,
                                               const float* __restrict__ beta,
                                               unsigned short* __restrict__ Yb, int n) {
    __shared__ unsigned short Bbf[128 * AST];
    __shared__ float scsh[256];
    gemm_tile(blockIdx.x, X, W, sums_part, gamma, beta, Yb, n, Bbf, scsh,
              threadIdx.x);
}

extern "C" void kernel_launch(void* const* d_in, const int* in_sizes, int n_in,
                              void* d_out, int out_size, void* d_ws, size_t ws_size,
                              hipStream_t stream) {
    const float* x     = (const float*)d_in[0];
    const int*   ei    = (const int*)d_in[1];
    const float* W1    = (const float*)d_in[2];
    // d_in[3] = b1 — cancels exactly in BatchNorm, unused
    const float* gamma = (const float*)d_in[4];
    const float* beta  = (const float*)d_in[5];
    const float* W2    = (const float*)d_in[6];
    const float* b2    = (const float*)d_in[7];
    float* out = (float*)d_out;

    int n = in_sizes[0] / D;   // 50000
    int E = in_sizes[1] / 2;   // 800000
    const int* src = ei;
    const int* dst = ei + E;
    int nchunks = (E + CHUNK - 1) / CHUNK;   // 391
    int ntiles = (n + 63) / 64;              // 782

    char* ws = (char*)d_ws;
    size_t off = 0;
    auto alloc = [&](size_t bytes) {
        char* p = ws + off;
        off = (off + bytes + 511) & ~(size_t)511;
        return p;
    };
    float*          agg       = (float*)alloc((size_t)n * D * sizeof(float));
    unsigned short* hbf       = (unsigned short*)alloc((size_t)n * D * 2);
    int*            rowcnt    = (int*)alloc((size_t)n * sizeof(int));
    float*          sums_part = (float*)alloc((size_t)NPART * 256 * sizeof(float));
    int*            csr       = (int*)alloc((size_t)n * RCAP * sizeof(int));

    // zero rowcnt + sums_part in one fill (contiguous in ws)
    size_t zspan = (size_t)((char*)(sums_part + NPART * 256) - (char*)rowcnt);
    hipMemsetAsync(rowcnt, 0, zspan, stream);

    // build padded CSR || GEMM1 (payload unscaled; norm per-edge in agg)
    k_build<<<nchunks + ntiles, 256, 0, stream>>>(src, dst, rowcnt, csr, E,
                                                  nchunks, x, W1, hbf, n);
    // conv1 aggregate -> agg, fused BN partial stats
    k_agg<<<(n + 3) / 4, 256, 0, stream>>>(hbf, csr, rowcnt, nullptr, agg,
                                           sums_part, n);
    // conv2 GEMM: hbf = bf16(relu(BN(agg)) @ W2), BN finalize in-block
    k_gemm2<<<ntiles, 256, 0, stream>>>(agg, W2, sums_part, gamma, beta, hbf, n);
    // conv2 aggregate + b2 -> out
    k_agg<<<(n + 3) / 4, 256, 0, stream>>>(hbf, csr, rowcnt, b2, out,
                                           nullptr, n);
}